// Round 4
// baseline (425.869 us; speedup 1.0000x reference)
//
#include <hip/hip_runtime.h>

#define T_DIM 512
#define L_DIM 128

typedef _Float16 h2 __attribute__((ext_vector_type(2)));

#if defined(__has_builtin)
#if __has_builtin(__builtin_amdgcn_fdot2)
#define HAS_FDOT2 1
#endif
#endif

__device__ __forceinline__ float fdot2_acc(h2 a, h2 b, float c) {
#ifdef HAS_FDOT2
    return __builtin_amdgcn_fdot2(a, b, c, false);
#else
    return c + (float)a.x * (float)b.x + (float)a.y * (float)b.y;
#endif
}

__device__ __forceinline__ unsigned int pack_u32(float a, float b) {
    return __builtin_bit_cast(unsigned int, __builtin_amdgcn_cvt_pkrtz(a, b));
}

#define H2C(x) __builtin_bit_cast(h2, (x))

// LDS-only barrier: drains lgkmcnt but NOT vmcnt, so global feats prefetch
// stays in flight across the step barrier.
__device__ __forceinline__ void lds_barrier() {
    asm volatile("s_waitcnt lgkmcnt(0)\n\ts_barrier" ::: "memory");
}

// Two waves (128 threads) = one batch chain. Lane owns ONE output column
// j = tid. Ehat = exp(transfer)/128 column j lives in VGPRs as 16 NAMED
// uint4 (64 VGPRs/lane) — half of round-3's footprint, fitting under the
// ~108-VGPR budget the allocator pinned us to (rounds 2+3 both spilled at
// exactly VGPR_Count=108 with a 128-word table; this is the fix).
//
// State u (128 f16 = 256 B) in LDS, double-buffered; every lane
// broadcast-reads all of it as 16 x ds_read_b128 (uniform addr). Per step:
// 64 fdot2 (4 chains x 16), 1 ds_write_b16, one 2-wave lgkm+s_barrier.
// Global feats prefetch (vmcnt) stays in flight across steps.

#define E_GROUPS(X) X(0) X(1) X(2) X(3) X(4) X(5) X(6) X(7) \
                    X(8) X(9) X(10) X(11) X(12) X(13) X(14) X(15)

__global__ __launch_bounds__(128, 1) void crf_fwd_kernel(
    const float* __restrict__ feats,
    const float* __restrict__ transfer,
    const int* __restrict__ target,
    const int* __restrict__ startp,
    const int* __restrict__ stopp,
    float* __restrict__ out)
{
    __shared__ unsigned int LdsU[2][64] __attribute__((aligned(16)));
    __shared__ float LdsRed[8];

    const int tid  = threadIdx.x;       // 0..127
    const int lane = tid & 63;
    const int wv   = tid >> 6;          // 0..1
    const int g    = tid;               // owned output column j
    const int b    = blockIdx.x;
    const int start = startp[0];
    const int stop  = stopp[0];
    const float* fbase = feats + (size_t)b * T_DIM * L_DIM;
    const float LOG128 = 4.852030263919617f;
    const float SCALE  = 0.0078125f;    // 1/128 folded into Ehat

    // ---- Ehat column g: 16 named uint4 (group v = i-rows 8v..8v+7) ----
#define DECL_E(v) uint4 E##v;
    E_GROUPS(DECL_E)
#undef DECL_E

#define LDT(r) transfer[(r) * L_DIM + g]
#define LOAD_E(v) { \
    float e0 = __expf(LDT(8*(v)+0)) * SCALE, e1 = __expf(LDT(8*(v)+1)) * SCALE; \
    float e2 = __expf(LDT(8*(v)+2)) * SCALE, e3 = __expf(LDT(8*(v)+3)) * SCALE; \
    float e4 = __expf(LDT(8*(v)+4)) * SCALE, e5 = __expf(LDT(8*(v)+5)) * SCALE; \
    float e6 = __expf(LDT(8*(v)+6)) * SCALE, e7 = __expf(LDT(8*(v)+7)) * SCALE; \
    E##v.x = pack_u32(e0, e1); E##v.y = pack_u32(e2, e3); \
    E##v.z = pack_u32(e4, e5); E##v.w = pack_u32(e6, e7); }
    E_GROUPS(LOAD_E)
#undef LOAD_E
#undef LDT

    const float trStop = transfer[g * L_DIM + stop];

    // ---- init: u = exp(f_1 + tr[start] + f_2)  (state includes f) ----
    {
        float v2 = fbase[1 * L_DIM + g] + fbase[2 * L_DIM + g]
                 + transfer[start * L_DIM + g];
        _Float16 h = (_Float16)__expf(v2);
        reinterpret_cast<unsigned short*>(&LdsU[0][0])[g] =
            __builtin_bit_cast(unsigned short, h);
    }
    // feats prefetch pipeline, 3 iterations deep (~HBM latency covered)
    float fa = fbase[3 * L_DIM + g];    // f_{t+1} consumed at t=2
    float fb = fbase[4 * L_DIM + g];
    float fc = fbase[5 * L_DIM + g];
    float S  = 0.f;
    lds_barrier();

    int cur = 0;
    float accF = 0.f;

    for (int t = 2; t <= T_DIM - 1; ++t) {
        int tp = t + 4; if (tp > T_DIM - 1) tp = T_DIM - 1;
        float fnew = fbase[tp * L_DIM + g];   // in flight (vmcnt)
        float e = __expf(fa);

        if ((t & 15) == 0) {                  // periodic renorm, off-path
            h2 h = H2C(LdsU[cur][0]);
            float u0 = (float)h.x;
            e *= 1.0f / u0;
            S += __logf(u0);
        }

        const uint4* U4p = reinterpret_cast<const uint4*>(&LdsU[cur][0]);
        float s0 = 0.f, s1 = 0.f, s2 = 0.f, s3 = 0.f;

#define DOT_G(v, AC) { \
        uint4 p = U4p[v]; \
        AC = fdot2_acc(H2C(p.x), H2C(E##v.x), AC); \
        AC = fdot2_acc(H2C(p.y), H2C(E##v.y), AC); \
        AC = fdot2_acc(H2C(p.z), H2C(E##v.z), AC); \
        AC = fdot2_acc(H2C(p.w), H2C(E##v.w), AC); }

        DOT_G(0,  s0) DOT_G(1,  s1) DOT_G(2,  s2) DOT_G(3,  s3)
        DOT_G(4,  s0) DOT_G(5,  s1) DOT_G(6,  s2) DOT_G(7,  s3)
        DOT_G(8,  s0) DOT_G(9,  s1) DOT_G(10, s2) DOT_G(11, s3)
        DOT_G(12, s0) DOT_G(13, s1) DOT_G(14, s2) DOT_G(15, s3)
#undef DOT_G

        float acc = (s0 + s1) + (s2 + s3);

        if (t < T_DIM - 1) {
            _Float16 h = (_Float16)(acc * e);
            reinterpret_cast<unsigned short*>(&LdsU[cur ^ 1][0])[g] =
                __builtin_bit_cast(unsigned short, h);
            lds_barrier();                    // 2-wave rendezvous, lgkm only
            cur ^= 1;
            fa = fb; fb = fc; fc = fnew;
        } else {
            accF = acc;
        }
    }

    // 510 dots, each carrying the folded 1/128
    S += 510.0f * LOG128;

    // ---- sentence = LSE_j(log u_j + S + tr[j,stop]) over 128 lanes ----
    float x  = __logf(accF) + S + trStop;
    float mx = x;
#pragma unroll
    for (int d = 1; d < 64; d <<= 1) mx = fmaxf(mx, __shfl_xor(mx, d));
    float ex = __expf(x - mx);
#pragma unroll
    for (int d = 1; d < 64; d <<= 1) ex += __shfl_xor(ex, d);
    if (lane == 0) { LdsRed[wv] = mx; LdsRed[2 + wv] = ex; }

    // ---- gold score: 4 t's per thread, coalesced target loads ----
    float es = 0.f, ts = 0.f;
    const int* tgt = target + b * T_DIM;
#pragma unroll
    for (int k = 0; k < 4; ++k) {
        int t = 1 + tid + (k << 7);
        if (t < T_DIM) {
            int tg = tgt[t];
            es += fbase[t * L_DIM + tg];
            int pr = (t == 1) ? start : tgt[t - 1];
            ts += transfer[pr * L_DIM + tg];
        }
    }
#pragma unroll
    for (int d = 1; d < 64; d <<= 1) {
        es += __shfl_xor(es, d);
        ts += __shfl_xor(ts, d);
    }
    if (lane == 0) { LdsRed[4 + wv] = es; LdsRed[6 + wv] = ts; }
    __syncthreads();

    if (tid == 0) {
        float M  = fmaxf(LdsRed[0], LdsRed[1]);
        float Ss = LdsRed[2] * __expf(LdsRed[0] - M)
                 + LdsRed[3] * __expf(LdsRed[1] - M);
        float sentence = M + __logf(Ss);
        float em = LdsRed[4] + LdsRed[5];
        float tn = LdsRed[6] + LdsRed[7];
        float emit0 = fbase[start];           // feats[b, 0, start]
        out[b] = sentence - __expf(emit0 + em + tn);
    }
}

extern "C" void kernel_launch(void* const* d_in, const int* in_sizes, int n_in,
                              void* d_out, int out_size, void* d_ws, size_t ws_size,
                              hipStream_t stream) {
    const float* feats    = (const float*)d_in[0];
    const float* transfer = (const float*)d_in[1];
    const int*   target   = (const int*)d_in[2];
    const int*   startp   = (const int*)d_in[3];
    const int*   stopp    = (const int*)d_in[4];
    float* outp = (float*)d_out;
    int B = in_sizes[0] / (T_DIM * L_DIM);
    hipLaunchKernelGGL(crf_fwd_kernel, dim3(B), dim3(128), 0, stream,
                       feats, transfer, target, startp, stopp, outp);
}